// Round 2
// baseline (925.427 us; speedup 1.0000x reference)
//
#include <hip/hip_runtime.h>

// InterHT score: per row b
//   hm,ha = head[b, :512], head[b, 512:]; tm,ta = tail[b,:512], tail[b,512:]
//   all four L2-normalized (v / max(||v||, 1e-12))
//   d = hm_n*(ta_n + 1) + rel[rid[b]] - tm_n*(ha_n + 1)
//   out[b] = -sqrt(sum(d*d))
//
// One wave (64 lanes) per row; lane l holds elements {4l..4l+3, 256+4l..256+4l+3}
// of each 512-wide part (2x 16B vector loads, fully coalesced 1KB segments).
// Norms + final reduction via __shfl_xor over 64 lanes — no LDS, no barriers.
//
// Note: __builtin_nontemporal_load requires a NATIVE clang vector type;
// HIP's float4 is a class. Use ext_vector_type(4) for streamed loads.

constexpr int EMB = 512;

typedef float fvec4 __attribute__((ext_vector_type(4)));

__device__ __forceinline__ float dot4(const fvec4 v) {
    return v.x * v.x + v.y * v.y + v.z * v.z + v.w * v.w;
}

__device__ __forceinline__ float wave_allreduce(float v) {
#pragma unroll
    for (int off = 32; off >= 1; off >>= 1)
        v += __shfl_xor(v, off, 64);
    return v;
}

__global__ __launch_bounds__(256) void interht_score_kernel(
    const float* __restrict__ head,
    const float* __restrict__ tail,
    const float* __restrict__ rel_emb,
    const int* __restrict__ rel_id,
    float* __restrict__ out,
    int batch)
{
    const int lane = threadIdx.x & 63;
    const int wave = threadIdx.x >> 6;
    const int row  = (blockIdx.x << 2) + wave;
    if (row >= batch) return;

    const fvec4* h = reinterpret_cast<const fvec4*>(head) + (size_t)row * (2 * EMB / 4);
    const fvec4* t = reinterpret_cast<const fvec4*>(tail) + (size_t)row * (2 * EMB / 4);

    // head row = 256 fvec4: [0..127] = main, [128..255] = aux
    fvec4 hm0 = __builtin_nontemporal_load(&h[lane]);
    fvec4 hm1 = __builtin_nontemporal_load(&h[64 + lane]);
    fvec4 ha0 = __builtin_nontemporal_load(&h[128 + lane]);
    fvec4 ha1 = __builtin_nontemporal_load(&h[192 + lane]);
    fvec4 tm0 = __builtin_nontemporal_load(&t[lane]);
    fvec4 tm1 = __builtin_nontemporal_load(&t[64 + lane]);
    fvec4 ta0 = __builtin_nontemporal_load(&t[128 + lane]);
    fvec4 ta1 = __builtin_nontemporal_load(&t[192 + lane]);

    const int rid = rel_id[row];
    const fvec4* r = reinterpret_cast<const fvec4*>(rel_emb) + (size_t)rid * (EMB / 4);
    fvec4 r0 = r[lane];
    fvec4 r1 = r[64 + lane];

    // four L2 norms (wave all-reduce each)
    const float s_hm = wave_allreduce(dot4(hm0) + dot4(hm1));
    const float s_ha = wave_allreduce(dot4(ha0) + dot4(ha1));
    const float s_tm = wave_allreduce(dot4(tm0) + dot4(tm1));
    const float s_ta = wave_allreduce(dot4(ta0) + dot4(ta1));

    const float i_hm = 1.0f / fmaxf(sqrtf(s_hm), 1e-12f);
    const float i_ha = 1.0f / fmaxf(sqrtf(s_ha), 1e-12f);
    const float i_tm = 1.0f / fmaxf(sqrtf(s_tm), 1e-12f);
    const float i_ta = 1.0f / fmaxf(sqrtf(s_ta), 1e-12f);

    float acc = 0.0f;
    auto accum = [&](float hm, float ha, float tm, float ta, float rr) {
        const float d = hm * i_hm * (ta * i_ta + 1.0f) + rr
                      - tm * i_tm * (ha * i_ha + 1.0f);
        acc = fmaf(d, d, acc);
    };
    accum(hm0.x, ha0.x, tm0.x, ta0.x, r0.x);
    accum(hm0.y, ha0.y, tm0.y, ta0.y, r0.y);
    accum(hm0.z, ha0.z, tm0.z, ta0.z, r0.z);
    accum(hm0.w, ha0.w, tm0.w, ta0.w, r0.w);
    accum(hm1.x, ha1.x, tm1.x, ta1.x, r1.x);
    accum(hm1.y, ha1.y, tm1.y, ta1.y, r1.y);
    accum(hm1.z, ha1.z, tm1.z, ta1.z, r1.z);
    accum(hm1.w, ha1.w, tm1.w, ta1.w, r1.w);

    acc = wave_allreduce(acc);
    if (lane == 0) out[row] = -sqrtf(acc);
}

extern "C" void kernel_launch(void* const* d_in, const int* in_sizes, int n_in,
                              void* d_out, int out_size, void* d_ws, size_t ws_size,
                              hipStream_t stream) {
    const float* head    = (const float*)d_in[0];
    const float* tail    = (const float*)d_in[1];
    const float* rel_emb = (const float*)d_in[2];
    const int*   rel_id  = (const int*)d_in[3];
    float* out = (float*)d_out;

    const int batch = in_sizes[3];           // relation_id count = BATCH
    const int rows_per_block = 4;            // 4 waves x 1 row each
    const int grid = (batch + rows_per_block - 1) / rows_per_block;

    interht_score_kernel<<<grid, 256, 0, stream>>>(head, tail, rel_emb, rel_id,
                                                   out, batch);
}